// Round 5
// baseline (711.968 us; speedup 1.0000x reference)
//
#include <hip/hip_runtime.h>
#include <stdint.h>

// FuncSelfAttention: b=4, s=256, E=256, H=8, d=32, p=16x16=256
// Round 5: all GEMMs use the m97-style 2-phase pipeline:
//   global_load_lds (16B) -> linear LDS dest, PRE-SWIZZLED global source,
//   double-buffered, ONE __syncthreads per K-step, next-tile loads issued
//   before the MFMA phase. 128x128 block tiles, BK=64, 4 waves of 64x64.
//
// Pipeline:
//   k_prep : W_qkv (split-major permuted) + W_out -> Wbf bf16 [1024][256]
//   k_tr   : seq f32 [bs][c][p] -> seqT bf16 [bs][p][c]
//   k_qk   : Q,K = W[0:512] x seqT^T -> [bh][s][dd][p]
//   k_v    : Wv x seqT-slices -> Vt [bh][dd*256+p][s]
//   k_scores: Q K^T, kc=4 K-split -> Sp f32
//   k_softmax: sum partials, softmax -> P bf16
//   k_av   : P x Vt^T -> SA [bs][c][p]
//   k_tr2  : SA -> SAT [bs][p][c]   (into dead Vt region)
//   k_out  : W_out x SAT^T + b -> out f32
//
// d_out: Qb 128MiB | Kb 128MiB (dead before k_out writes 256MiB f32 at base)
// d_ws : Vt 128MiB (-> SAT) | R 128MiB (seqT -> Sp -> SA) | Pb 4MiB | Wbf
//        (273MiB envelope, proven in round 4)

#define DI __device__ __forceinline__

typedef __attribute__((ext_vector_type(4))) float  f32x4;
typedef __attribute__((ext_vector_type(8))) short  s16x8;
typedef __attribute__((ext_vector_type(4))) short  s16x4;
typedef __attribute__((ext_vector_type(8))) __bf16 bf16x8;

DI unsigned short f2bf(float f) {
    unsigned int u = __builtin_bit_cast(unsigned int, f);
    u = (u + 0x7fffu + ((u >> 16) & 1u)) >> 16;
    return (unsigned short)u;
}
DI bf16x8 asbf(s16x8 v) { return __builtin_bit_cast(bf16x8, v); }
#define MFMA16(a, b, c) __builtin_amdgcn_mfma_f32_16x16x32_bf16((a), (b), (c), 0, 0, 0)

#define GLOAD16(g, l) __builtin_amdgcn_global_load_lds( \
    (const __attribute__((address_space(1))) unsigned int*)(g), \
    (__attribute__((address_space(3))) unsigned int*)(l), 16, 0, 0)

// ---- stage one [128 rows][64 k] bf16 tile: 4 global_load_lds per wave ------
// Per-lane global source is pre-swizzled: lane l of wave w, iteration i
// covers row w*32+i*8+(l>>3), physical chunk l&7 <- global chunk (l&7)^(l>>3).
// gA must already include: base + (w*32 + (l>>3))*stride + ((l&7)^(l>>3))*8 + k0.
DI void stage_tile(const unsigned short* gp, size_t stride,
                   unsigned short* lbase, int w) {
#pragma unroll
    for (int i = 0; i < 4; i++)
        GLOAD16(gp + (size_t)(i * 8) * stride, lbase + (w * 4 + i) * 512);
}

// ---- MFMA phase, wave tile 64x64 (mf=4, nf=4), BK=64, swizzled reads -------
DI void mfma_44(const unsigned short* __restrict__ Al,
                const unsigned short* __restrict__ Bl,
                f32x4 acc[4][4], int wm, int wn, int lg, int lr) {
#pragma unroll
    for (int kk = 0; kk < 2; kk++) {
        int off = (((kk * 4 + lg) ^ (lr & 7)) << 3);
        s16x8 af[4];
#pragma unroll
        for (int m = 0; m < 4; m++)
            af[m] = *(const s16x8*)&Al[(wm + m * 16 + lr) * 64 + off];
        s16x8 bf[4];
#pragma unroll
        for (int n = 0; n < 4; n++)
            bf[n] = *(const s16x8*)&Bl[(wn + n * 16 + lr) * 64 + off];
#pragma unroll
        for (int n = 0; n < 4; n++) {
            bf16x8 bv = asbf(bf[n]);
#pragma unroll
            for (int m = 0; m < 4; m++)
                acc[m][n] = MFMA16(asbf(af[m]), bv, acc[m][n]);
        }
    }
}

// Common per-thread geometry for the 2-phase core.
#define CORE_SETUP()                                            \
    const int tid = threadIdx.x, ln = tid & 63, w = tid >> 6;   \
    const int wm = (w >> 1) * 64, wn = (w & 1) * 64;            \
    const int lg = ln >> 4, lr = ln & 15;                       \
    const int srow = ln >> 3;                                   \
    const int schk = (ln & 7) ^ srow;                           \
    f32x4 acc[4][4];                                            \
    { const f32x4 z4 = {0.f, 0.f, 0.f, 0.f};                    \
      for (int m = 0; m < 4; m++)                               \
        for (int n = 0; n < 4; n++) acc[m][n] = z4; }

// 2-phase main loop over NT K-steps (k advances 64 elements/step).
#define CORE_LOOP(NT, gA, As, gB, Bs)                                   \
    stage_tile(gA, As, Ab[0], w);                                       \
    stage_tile(gB, Bs, Bb[0], w);                                       \
    __syncthreads();                                                    \
    for (int t = 0; t < (NT); t++) {                                    \
        if (t + 1 < (NT)) {                                             \
            stage_tile(gA + (size_t)(t + 1) * 64, As, Ab[(t + 1) & 1], w); \
            stage_tile(gB + (size_t)(t + 1) * 64, Bs, Bb[(t + 1) & 1], w); \
        }                                                               \
        mfma_44(Ab[t & 1], Bb[t & 1], acc, wm, wn, lg, lr);             \
        __syncthreads();                                                \
    }

// ===========================================================================
// k_prep: Wbf[1024][256]: rows 0..767 = W_qkv permuted (r = split*256+h*32+dd
// from source row h*96+split*32+dd), rows 768..1023 = W_out.
// ===========================================================================
__global__ __launch_bounds__(64) void k_prep(
    const float* __restrict__ Wqkv, const float* __restrict__ Wout,
    unsigned short* __restrict__ Wbf)
{
    int r = blockIdx.x, ln = threadIdx.x;
    const float* src;
    if (r < 768) {
        int split = r >> 8, hd = r & 255;
        src = Wqkv + (size_t)(((hd >> 5) * 96) + split * 32 + (hd & 31)) * 256;
    } else {
        src = Wout + (size_t)(r - 768) * 256;
    }
    f32x4 v = *(const f32x4*)(src + ln * 4);
    s16x4 h = {(short)f2bf(v.x), (short)f2bf(v.y), (short)f2bf(v.z), (short)f2bf(v.w)};
    *(s16x4*)&Wbf[(size_t)r * 256 + ln * 4] = h;
}

// ===========================================================================
// k_tr: seq f32 [bs][256 c][256 p] -> seqT bf16 [bs][256 p][256 c].
// ===========================================================================
__global__ __launch_bounds__(256) void k_tr(
    const float* __restrict__ seq, unsigned short* __restrict__ seqT)
{
    const int bs = blockIdx.x, tid = threadIdx.x;
    __shared__ __align__(16) unsigned short T[64][264];
    const float* src = seq + (size_t)bs * 65536;
    unsigned short* dst = seqT + (size_t)bs * 65536;

    for (int co = 0; co < 256; co += 64) {
        {
            int r = tid >> 2, p0 = (tid & 3) * 64;
            const float* s = src + (size_t)(co + r) * 256 + p0;
#pragma unroll
            for (int i = 0; i < 8; i++) {
                f32x4 a = *(const f32x4*)(s + i * 8);
                f32x4 b = *(const f32x4*)(s + i * 8 + 4);
                s16x8 h = {(short)f2bf(a.x), (short)f2bf(a.y), (short)f2bf(a.z),
                           (short)f2bf(a.w), (short)f2bf(b.x), (short)f2bf(b.y),
                           (short)f2bf(b.z), (short)f2bf(b.w)};
                *(s16x8*)&T[r][p0 + i * 8] = h;
            }
        }
        __syncthreads();
        {
            unsigned short e[64];
#pragma unroll
            for (int c = 0; c < 64; c++) e[c] = T[c][tid];
            unsigned short* d = dst + (size_t)tid * 256 + co;
#pragma unroll
            for (int j = 0; j < 8; j++) {
                s16x8 v = {(short)e[j * 8 + 0], (short)e[j * 8 + 1],
                           (short)e[j * 8 + 2], (short)e[j * 8 + 3],
                           (short)e[j * 8 + 4], (short)e[j * 8 + 5],
                           (short)e[j * 8 + 6], (short)e[j * 8 + 7]};
                *(s16x8*)(d + j * 8) = v;
            }
        }
        __syncthreads();
    }
}

// ===========================================================================
// k_tr2: SA bf16 [bs][256 c][256 p] -> SAT bf16 [bs][256 p][256 c].
// ===========================================================================
__global__ __launch_bounds__(256) void k_tr2(
    const unsigned short* __restrict__ SA, unsigned short* __restrict__ SAT)
{
    const int bs = blockIdx.x, tid = threadIdx.x;
    __shared__ __align__(16) unsigned short T[64][264];
    const unsigned short* src = SA + (size_t)bs * 65536;
    unsigned short* dst = SAT + (size_t)bs * 65536;

    for (int co = 0; co < 256; co += 64) {
        {
            int r = tid >> 2, p0 = (tid & 3) * 64;
            const unsigned short* s = src + (size_t)(co + r) * 256 + p0;
#pragma unroll
            for (int i = 0; i < 8; i++)
                *(s16x8*)&T[r][p0 + i * 8] = *(const s16x8*)(s + i * 8);
        }
        __syncthreads();
        {
            unsigned short e[64];
#pragma unroll
            for (int c = 0; c < 64; c++) e[c] = T[c][tid];
            unsigned short* d = dst + (size_t)tid * 256 + co;
#pragma unroll
            for (int j = 0; j < 8; j++) {
                s16x8 v = {(short)e[j * 8 + 0], (short)e[j * 8 + 1],
                           (short)e[j * 8 + 2], (short)e[j * 8 + 3],
                           (short)e[j * 8 + 4], (short)e[j * 8 + 5],
                           (short)e[j * 8 + 6], (short)e[j * 8 + 7]};
                *(s16x8*)(d + j * 8) = v;
            }
        }
        __syncthreads();
    }
}

// ===========================================================================
// k_qk: Q,K projection.  grid 8192: wk = bs*8 + mt*2 + nt (XCD co-located).
// M=512 (Q||K), N=256 (p), K=256 (c).
// ===========================================================================
__global__ __launch_bounds__(256, 2) void k_qk(
    const unsigned short* __restrict__ seqT, const unsigned short* __restrict__ Wbf,
    unsigned short* __restrict__ Qb, unsigned short* __restrict__ Kb)
{
    const int bid = blockIdx.x;
    const int wk = (bid & 7) * 1024 + (bid >> 3);
    const int bs = wk >> 3, mt = (wk >> 1) & 3, nt = wk & 1;
    const int b = bs >> 8, s = bs & 255;

    __shared__ __align__(16) unsigned short Ab[2][8192];
    __shared__ __align__(16) unsigned short Bb[2][8192];

    CORE_SETUP();

    const unsigned short* gA = Wbf + (size_t)(mt * 128 + w * 32 + srow) * 256 + schk * 8;
    const unsigned short* gB = seqT + (size_t)bs * 65536
        + (size_t)(nt * 128 + w * 32 + srow) * 256 + schk * 8;

    CORE_LOOP(4, gA, 256, gB, 256);

#pragma unroll
    for (int m = 0; m < 4; m++) {
#pragma unroll
        for (int rr = 0; rr < 4; rr++) {
            int o512 = mt * 128 + wm + m * 16 + lg * 4 + rr;
            int o = o512 & 255;
            unsigned short* dst = (o512 >> 8) ? Kb : Qb;
            size_t base = ((size_t)((b * 8 + (o >> 5)) * 256 + s)) * 8192
                        + (size_t)(o & 31) * 256 + nt * 128 + wn + lr;
#pragma unroll
            for (int n = 0; n < 4; n++)
                dst[base + n * 16] = f2bf(acc[m][n][rr]);
        }
    }
}

// ===========================================================================
// k_v: V projection -> Vt[bh][dd*256+p][s].  grid 4096: x = ((b*256+p)*2+mt)*2+nt
// M=256 (h,dd), N=256 (s), K=256 (c).  B rows = seqT[(b,s)][p][:] stride 65536.
// ===========================================================================
__global__ __launch_bounds__(256, 2) void k_v(
    const unsigned short* __restrict__ seqT, const unsigned short* __restrict__ Wbf,
    unsigned short* __restrict__ Vt)
{
    const int x = blockIdx.x;
    const int b = x >> 10, p = (x >> 2) & 255, mt = (x >> 1) & 1, nt = x & 1;

    __shared__ __align__(16) unsigned short Ab[2][8192];
    __shared__ __align__(16) unsigned short Bb[2][8192];

    CORE_SETUP();

    const unsigned short* gA = Wbf + (size_t)(512 + mt * 128 + w * 32 + srow) * 256 + schk * 8;
    const unsigned short* gB = seqT
        + (size_t)(b * 256 + nt * 128 + w * 32 + srow) * 65536
        + (size_t)p * 256 + schk * 8;

    CORE_LOOP(4, gA, 256, gB, 65536);

#pragma unroll
    for (int m = 0; m < 4; m++) {
#pragma unroll
        for (int rr = 0; rr < 4; rr++) {
            int o = mt * 128 + wm + m * 16 + lg * 4 + rr;   // h*32+dd
            size_t base = ((size_t)(b * 8 + (o >> 5)) * 8192
                         + (size_t)(o & 31) * 256 + p) * 256 + nt * 128 + wn + lr;
#pragma unroll
            for (int n = 0; n < 4; n++)
                Vt[base + n * 16] = f2bf(acc[m][n][rr]);
        }
    }
}

// ===========================================================================
// k_scores: Q K^T partials.  grid (16, 32): x = (mt*2+st)*4+kc, y = bh.
// M=256 (q), N=256 (ks), K-slice 2048 per kc (kc=4) -> Sp[kc] f32 unscaled.
// ===========================================================================
__global__ __launch_bounds__(256, 2) void k_scores(
    const unsigned short* __restrict__ Qb, const unsigned short* __restrict__ Kb,
    float* __restrict__ Sp)
{
    const int bh = blockIdx.y;
    const int kc = blockIdx.x & 3, st = (blockIdx.x >> 2) & 1, mt = blockIdx.x >> 3;

    __shared__ __align__(16) unsigned short Ab[2][8192];
    __shared__ __align__(16) unsigned short Bb[2][8192];

    CORE_SETUP();

    const unsigned short* gA = Qb + (size_t)(bh * 256 + mt * 128 + w * 32 + srow) * 8192
                             + kc * 2048 + schk * 8;
    const unsigned short* gB = Kb + (size_t)(bh * 256 + st * 128 + w * 32 + srow) * 8192
                             + kc * 2048 + schk * 8;

    CORE_LOOP(32, gA, 8192, gB, 8192);

    float* dst = Sp + (size_t)kc * 2097152
               + (size_t)(bh * 256 + mt * 128 + wm) * 256 + st * 128 + wn;
#pragma unroll
    for (int m = 0; m < 4; m++) {
#pragma unroll
        for (int rr = 0; rr < 4; rr++) {
            float* d = dst + (size_t)(m * 16 + lg * 4 + rr) * 256 + lr;
#pragma unroll
            for (int n = 0; n < 4; n++)
                d[n * 16] = acc[m][n][rr];
        }
    }
}

// ===========================================================================
// k_softmax: sum 4 partials, scale, softmax -> P bf16.  grid 2048 x 256.
// ===========================================================================
__global__ __launch_bounds__(256) void k_softmax(
    const float* __restrict__ Sp, unsigned short* __restrict__ Pb)
{
    const int tid = threadIdx.x, ln = tid & 63;
    const int row = blockIdx.x * 4 + (tid >> 6);
    const float scale = 0.011048543456039806f;  // 1/sqrt(32*256)

    const float* p0 = Sp + (size_t)row * 256 + ln * 4;
    f32x4 v = *(const f32x4*)p0;
#pragma unroll
    for (int k = 1; k < 4; k++)
        v += *(const f32x4*)(p0 + (size_t)k * 2097152);
    v *= scale;

    float m = fmaxf(fmaxf(v.x, v.y), fmaxf(v.z, v.w));
#pragma unroll
    for (int off = 32; off; off >>= 1) m = fmaxf(m, __shfl_xor(m, off));
    float e0 = __expf(v.x - m), e1 = __expf(v.y - m);
    float e2 = __expf(v.z - m), e3 = __expf(v.w - m);
    float sum = e0 + e1 + e2 + e3;
#pragma unroll
    for (int off = 32; off; off >>= 1) sum += __shfl_xor(sum, off);
    float inv = 1.f / sum;
    s16x4 p = {(short)f2bf(e0 * inv), (short)f2bf(e1 * inv),
               (short)f2bf(e2 * inv), (short)f2bf(e3 * inv)};
    *(s16x4*)(Pb + (size_t)row * 256 + ln * 4) = p;
}

// ===========================================================================
// k_av: SA = P V.  grid (128, 32): x = ft*2+mt, y = bh.
// M=256 (q), N=8192 (f = dd*256+p), K=256 (ks).
// ===========================================================================
__global__ __launch_bounds__(256, 2) void k_av(
    const unsigned short* __restrict__ Pb, const unsigned short* __restrict__ Vt,
    unsigned short* __restrict__ SAb)
{
    const int bh = blockIdx.y;
    const int mt = blockIdx.x & 1, ft = blockIdx.x >> 1;
    const int b = bh >> 3, h = bh & 7;

    __shared__ __align__(16) unsigned short Ab[2][8192];
    __shared__ __align__(16) unsigned short Bb[2][8192];

    CORE_SETUP();

    const unsigned short* gA = Pb + (size_t)(bh * 256 + mt * 128 + w * 32 + srow) * 256
                             + schk * 8;
    const unsigned short* gB = Vt + (size_t)bh * 2097152
                             + (size_t)(ft * 128 + w * 32 + srow) * 256 + schk * 8;

    CORE_LOOP(4, gA, 256, gB, 256);

#pragma unroll
    for (int m = 0; m < 4; m++) {
#pragma unroll
        for (int rr = 0; rr < 4; rr++) {
            int q = mt * 128 + wm + m * 16 + lg * 4 + rr;
            size_t base = (size_t)(b * 256 + q) * 65536 + h * 8192
                        + ft * 128 + wn + lr;
#pragma unroll
            for (int n = 0; n < 4; n++)
                SAb[base + n * 16] = f2bf(acc[m][n][rr]);
        }
    }
}

// ===========================================================================
// k_out: out = W_out SAT^T + b.  grid (4, 1024): x = mt*2+nt, y = bs.
// M=256 (o), N=256 (p), K=256 (c).
// ===========================================================================
__global__ __launch_bounds__(256, 2) void k_out(
    const unsigned short* __restrict__ SAT, const unsigned short* __restrict__ Wbf,
    const float* __restrict__ bias, float* __restrict__ out)
{
    const int bs = blockIdx.y;
    const int mt = blockIdx.x >> 1, nt = blockIdx.x & 1;

    __shared__ __align__(16) unsigned short Ab[2][8192];
    __shared__ __align__(16) unsigned short Bb[2][8192];

    CORE_SETUP();

    const unsigned short* gA = Wbf + (size_t)(768 + mt * 128 + w * 32 + srow) * 256
                             + schk * 8;
    const unsigned short* gB = SAT + (size_t)bs * 65536
                             + (size_t)(nt * 128 + w * 32 + srow) * 256 + schk * 8;

    CORE_LOOP(4, gA, 256, gB, 256);

#pragma unroll
    for (int m = 0; m < 4; m++) {
#pragma unroll
        for (int rr = 0; rr < 4; rr++) {
            int o = mt * 128 + wm + m * 16 + lg * 4 + rr;
            float bo = bias[o];
            float* d = out + ((size_t)bs * 256 + o) * 256 + nt * 128 + wn + lr;
#pragma unroll
            for (int n = 0; n < 4; n++)
                d[n * 16] = acc[m][n][rr] + bo;
        }
    }
}

// ---------------------------------------------------------------------------
extern "C" void kernel_launch(void* const* d_in, const int* in_sizes, int n_in,
                              void* d_out, int out_size, void* d_ws, size_t ws_size,
                              hipStream_t stream)
{
    const float* seq  = (const float*)d_in[0];
    const float* Wqkv = (const float*)d_in[1];
    const float* Wout = (const float*)d_in[2];
    const float* bout = (const float*)d_in[3];

    // d_out: Q | K (dead before k_out writes the final f32 output at base)
    unsigned short* Qb = (unsigned short*)d_out;
    unsigned short* Kb = Qb + 67108864;

    // d_ws: Vt (-> SAT after k_av) | R (seqT -> Sp -> SA) | Pb | Wbf
    unsigned short* Vt   = (unsigned short*)d_ws;
    unsigned short* SAT  = Vt;
    unsigned short* seqT = Vt + 67108864;
    float*          Sp   = (float*)seqT;
    unsigned short* SAb  = seqT;
    unsigned short* Pb   = (unsigned short*)d_ws + 134217728;
    unsigned short* Wbf  = Pb + 2097152;

    float* out = (float*)d_out;

    k_prep<<<dim3(1024), dim3(64), 0, stream>>>(Wqkv, Wout, Wbf);
    k_tr<<<dim3(1024), dim3(256), 0, stream>>>(seq, seqT);
    k_qk<<<dim3(8192), dim3(256), 0, stream>>>(seqT, Wbf, Qb, Kb);
    k_v<<<dim3(4096), dim3(256), 0, stream>>>(seqT, Wbf, Vt);
    k_scores<<<dim3(16, 32), dim3(256), 0, stream>>>(Qb, Kb, Sp);
    k_softmax<<<dim3(2048), dim3(256), 0, stream>>>(Sp, Pb);
    k_av<<<dim3(128, 32), dim3(256), 0, stream>>>(Pb, Vt, SAb);
    k_tr2<<<dim3(1024), dim3(256), 0, stream>>>(SAb, SAT);
    k_out<<<dim3(4, 1024), dim3(256), 0, stream>>>(SAT, Wbf, bout, out);
}

// Round 6
// 552.779 us; speedup vs baseline: 1.2880x; 1.2880x over previous
//
#include <hip/hip_runtime.h>
#include <stdint.h>

// FuncSelfAttention: b=4, s=256, E=256, H=8, d=32, p=16x16=256
// Round 6: the K=256 GEMMs (qkv-proj, AV, out-proj) use an A-RESIDENT
// STREAMING structure: each wave holds its 64-row x 256-k A-slice in VGPRs
// (32 s16x8 = 128 VGPR), B-tiles [64 n x 256 k] are double-buffered in LDS
// via global_load_lds (pre-swizzled source), one barrier per N-tile, stores
// after the barrier. Long N-streams (8-32 tiles/block) amortize fill/drain.
// k_scores (K=8192) keeps the classic dbuf pipeline; k_tr2 is eliminated by
// choosing Vt = [bh][p*32+dd][s] so k_av writes SAT [bs][p][c] directly.
//
// d_out: Qb 128MiB | Kb 128MiB (dead before k_out writes 256MiB f32 at base)
// d_ws : Vt 128MiB | R 128MiB (seqT -> Sp -> SAT) | Pb 4MiB | Wbf 0.5MiB

#define DI __device__ __forceinline__

typedef __attribute__((ext_vector_type(4))) float  f32x4;
typedef __attribute__((ext_vector_type(8))) short  s16x8;
typedef __attribute__((ext_vector_type(4))) short  s16x4;
typedef __attribute__((ext_vector_type(8))) __bf16 bf16x8;

DI unsigned short f2bf(float f) {
    unsigned int u = __builtin_bit_cast(unsigned int, f);
    u = (u + 0x7fffu + ((u >> 16) & 1u)) >> 16;
    return (unsigned short)u;
}
DI bf16x8 asbf(s16x8 v) { return __builtin_bit_cast(bf16x8, v); }
#define MFMA16(a, b, c) __builtin_amdgcn_mfma_f32_16x16x32_bf16((a), (b), (c), 0, 0, 0)

#define GLOAD16(g, l) __builtin_amdgcn_global_load_lds( \
    (const __attribute__((address_space(1))) unsigned int*)(g), \
    (__attribute__((address_space(3))) unsigned int*)(l), 16, 0, 0)

// ===========================================================================
// Stream-GEMM building blocks (4 waves, wave = 64 M-rows, K = 256 resident)
// ===========================================================================

// Load the wave's A-slice [64 rows x 256 k] into 32 s16x8 frags (128 VGPR).
// Row stride of A source is 256 elements.
DI void sgk_loadA(const unsigned short* __restrict__ Asrc,
                  s16x8 af[4][8], int wm, int lg, int lr) {
#pragma unroll
    for (int m = 0; m < 4; m++)
#pragma unroll
        for (int kf = 0; kf < 8; kf++)
            af[m][kf] = *(const s16x8*)(Asrc + (size_t)(wm + m * 16 + lr) * 256
                                        + kf * 32 + lg * 8);
}

// Stage one B-tile [64 n x 256 k] (32KB) into LDS via 8 global_load_lds per
// thread. LDS dest is LINEAR (chunk c = i*256+tid); the global source is
// pre-swizzled so reads use chunk ^ (row&7). src = per-thread base
// (includes (tid>>5) row offset and swizzled chunk offset) + tile offset.
DI void sgk_stage(const unsigned short* src, size_t rstride,
                  unsigned short* lds, int tid) {
#pragma unroll
    for (int i = 0; i < 8; i++)
        GLOAD16(src + (size_t)(i * 8) * rstride, lds + ((i * 256 + tid) << 3));
}

// MFMA one N-tile: acc[m][n] = A-slice x B-tile (64x64 out, full K=256).
DI void sgk_mfma(const unsigned short* __restrict__ Bl,
                 const s16x8 af[4][8], f32x4 acc[4][4], int lg, int lr) {
    const f32x4 z4 = {0.f, 0.f, 0.f, 0.f};
    {   // kf = 0 initializes acc (no explicit zeroing pass)
        s16x8 bfv[4];
#pragma unroll
        for (int n = 0; n < 4; n++)
            bfv[n] = *(const s16x8*)&Bl[(n * 16 + lr) * 256 + ((lg ^ (lr & 7)) << 3)];
#pragma unroll
        for (int n = 0; n < 4; n++) {
            bf16x8 bv = asbf(bfv[n]);
#pragma unroll
            for (int m = 0; m < 4; m++)
                acc[m][n] = MFMA16(asbf(af[m][0]), bv, z4);
        }
    }
#pragma unroll
    for (int kf = 1; kf < 8; kf++) {
        s16x8 bfv[4];
#pragma unroll
        for (int n = 0; n < 4; n++)
            bfv[n] = *(const s16x8*)&Bl[(n * 16 + lr) * 256
                                        + (((kf * 4 + lg) ^ (lr & 7)) << 3)];
#pragma unroll
        for (int n = 0; n < 4; n++) {
            bf16x8 bv = asbf(bfv[n]);
#pragma unroll
            for (int m = 0; m < 4; m++)
                acc[m][n] = MFMA16(asbf(af[m][kf]), bv, acc[m][n]);
        }
    }
}

#define SGK_SETUP()                                           \
    const int tid = threadIdx.x, ln = tid & 63, w = tid >> 6; \
    const int wm = w * 64;                                    \
    const int lg = ln >> 4, lr = ln & 15;                     \
    const size_t swoff = (size_t)(((tid & 31) ^ ((tid >> 5) & 7)) * 8); \
    const size_t srow = (size_t)(tid >> 5);

// ===========================================================================
// k_prep: Wbf[1024][256]: rows 0..767 = W_qkv permuted (r = split*256+h*32+dd
// from source row h*96+split*32+dd), rows 768..1023 = W_out.
// ===========================================================================
__global__ __launch_bounds__(64) void k_prep(
    const float* __restrict__ Wqkv, const float* __restrict__ Wout,
    unsigned short* __restrict__ Wbf)
{
    int r = blockIdx.x, ln = threadIdx.x;
    const float* src;
    if (r < 768) {
        int split = r >> 8, hd = r & 255;
        src = Wqkv + (size_t)(((hd >> 5) * 96) + split * 32 + (hd & 31)) * 256;
    } else {
        src = Wout + (size_t)(r - 768) * 256;
    }
    f32x4 v = *(const f32x4*)(src + ln * 4);
    s16x4 h = {(short)f2bf(v.x), (short)f2bf(v.y), (short)f2bf(v.z), (short)f2bf(v.w)};
    *(s16x4*)&Wbf[(size_t)r * 256 + ln * 4] = h;
}

// ===========================================================================
// k_tr: seq f32 [bs][256 c][256 p] -> seqT bf16 [bs][256 p][256 c].
// ===========================================================================
__global__ __launch_bounds__(256) void k_tr(
    const float* __restrict__ seq, unsigned short* __restrict__ seqT)
{
    const int bs = blockIdx.x, tid = threadIdx.x;
    __shared__ __align__(16) unsigned short T[64][264];
    const float* src = seq + (size_t)bs * 65536;
    unsigned short* dst = seqT + (size_t)bs * 65536;

    for (int co = 0; co < 256; co += 64) {
        {
            int r = tid >> 2, p0 = (tid & 3) * 64;
            const float* s = src + (size_t)(co + r) * 256 + p0;
#pragma unroll
            for (int i = 0; i < 8; i++) {
                f32x4 a = *(const f32x4*)(s + i * 8);
                f32x4 b = *(const f32x4*)(s + i * 8 + 4);
                s16x8 h = {(short)f2bf(a.x), (short)f2bf(a.y), (short)f2bf(a.z),
                           (short)f2bf(a.w), (short)f2bf(b.x), (short)f2bf(b.y),
                           (short)f2bf(b.z), (short)f2bf(b.w)};
                *(s16x8*)&T[r][p0 + i * 8] = h;
            }
        }
        __syncthreads();
        {
            unsigned short e[64];
#pragma unroll
            for (int c = 0; c < 64; c++) e[c] = T[c][tid];
            unsigned short* d = dst + (size_t)tid * 256 + co;
#pragma unroll
            for (int j = 0; j < 8; j++) {
                s16x8 v = {(short)e[j * 8 + 0], (short)e[j * 8 + 1],
                           (short)e[j * 8 + 2], (short)e[j * 8 + 3],
                           (short)e[j * 8 + 4], (short)e[j * 8 + 5],
                           (short)e[j * 8 + 6], (short)e[j * 8 + 7]};
                *(s16x8*)(d + j * 8) = v;
            }
        }
        __syncthreads();
    }
}

// ===========================================================================
// k_qkT: Q,K projection (stream).  grid 512: x = mt*256 + g.
// Block: M-tile = split mt (256 rows), streams 16 N-tiles (4 tokens x 256 p).
// ===========================================================================
__global__ __launch_bounds__(256, 2) void k_qkT(
    const unsigned short* __restrict__ seqT, const unsigned short* __restrict__ Wbf,
    unsigned short* __restrict__ Qb, unsigned short* __restrict__ Kb)
{
    const int mt = blockIdx.x >> 8, g = blockIdx.x & 255;

    __shared__ __align__(16) unsigned short Bb[2][16384];

    SGK_SETUP();

    s16x8 af[4][8];
    sgk_loadA(Wbf + (size_t)mt * 65536, af, wm, lg, lr);

    const unsigned short* Bsrc = seqT + (size_t)g * 262144 + srow * 256 + swoff;
    unsigned short* const dstB = mt ? Kb : Qb;

    sgk_stage(Bsrc, 256, Bb[0], tid);
    __syncthreads();

    for (int t = 0; t < 16; t++) {
        if (t + 1 < 16)
            sgk_stage(Bsrc + (size_t)(t + 1) * 16384, 256, Bb[(t + 1) & 1], tid);
        f32x4 acc[4][4];
        sgk_mfma(Bb[t & 1], af, acc, lg, lr);
        __syncthreads();

        const int bs = g * 4 + (t >> 2);
        const int b = bs >> 8, s = bs & 255;
        const int pb = (t & 3) * 64;
#pragma unroll
        for (int m = 0; m < 4; m++) {
#pragma unroll
            for (int rr = 0; rr < 4; rr++) {
                int oo = wm + m * 16 + lg * 4 + rr;
                size_t base = ((size_t)((b * 8 + (oo >> 5)) * 256 + s)) * 8192
                            + (size_t)(oo & 31) * 256 + pb + lr;
#pragma unroll
                for (int n = 0; n < 4; n++)
                    dstB[base + n * 16] = f2bf(acc[m][n][rr]);
            }
        }
    }
}

// ===========================================================================
// k_vT: V projection (stream) -> Vt[bh][p*32+dd][s].  grid 512: x = b*128+pg.
// Block streams 8 N-tiles: p = pg*2 + (t>>2), s-range (t&3)*64.
// B rows = seqT[(b,s)][p][:], row stride 65536.
// ===========================================================================
__global__ __launch_bounds__(256, 2) void k_vT(
    const unsigned short* __restrict__ seqT, const unsigned short* __restrict__ Wbf,
    unsigned short* __restrict__ Vt)
{
    const int b = blockIdx.x >> 7, pg = blockIdx.x & 127;

    __shared__ __align__(16) unsigned short Bb[2][16384];

    SGK_SETUP();

    s16x8 af[4][8];
    sgk_loadA(Wbf + 131072, af, wm, lg, lr);

    const unsigned short* Bsrc = seqT + ((size_t)b * 256 + srow) * 65536 + swoff;

#define VT_TILE(t) (Bsrc + (size_t)(pg * 2 + ((t) >> 2)) * 256 \
                         + (size_t)(((t) & 3) * 64) * 65536)

    sgk_stage(VT_TILE(0), 65536, Bb[0], tid);
    __syncthreads();

    for (int t = 0; t < 8; t++) {
        if (t + 1 < 8)
            sgk_stage(VT_TILE(t + 1), 65536, Bb[(t + 1) & 1], tid);
        f32x4 acc[4][4];
        sgk_mfma(Bb[t & 1], af, acc, lg, lr);
        __syncthreads();

        const int p = pg * 2 + (t >> 2);
        const int sb = (t & 3) * 64;
#pragma unroll
        for (int m = 0; m < 4; m++) {
#pragma unroll
            for (int rr = 0; rr < 4; rr++) {
                int o = wm + m * 16 + lg * 4 + rr;    // h*32+dd
                size_t base = (size_t)(b * 8 + (o >> 5)) * 2097152
                            + (size_t)(p * 32 + (o & 31)) * 256 + sb + lr;
#pragma unroll
                for (int n = 0; n < 4; n++)
                    Vt[base + n * 16] = f2bf(acc[m][n][rr]);
            }
        }
    }
#undef VT_TILE
}

// ===========================================================================
// k_avT: SA = P V (stream) -> SAT [bs][p][c].  grid 512: x = bh*16 + nsl.
// Block streams 8 N-tiles of 64 f (f = p*32+dd), A = P[bh] (q x ks).
// ===========================================================================
__global__ __launch_bounds__(256, 2) void k_avT(
    const unsigned short* __restrict__ Pb, const unsigned short* __restrict__ Vt,
    unsigned short* __restrict__ SAT)
{
    const int bh = blockIdx.x >> 4, nsl = blockIdx.x & 15;
    const int b = bh >> 3, h = bh & 7;

    __shared__ __align__(16) unsigned short Bb[2][16384];

    SGK_SETUP();

    s16x8 af[4][8];
    sgk_loadA(Pb + (size_t)bh * 65536, af, wm, lg, lr);

    const unsigned short* Bsrc = Vt + (size_t)bh * 2097152
                               + (size_t)(nsl * 512) * 256 + srow * 256 + swoff;

    sgk_stage(Bsrc, 256, Bb[0], tid);
    __syncthreads();

    for (int t = 0; t < 8; t++) {
        if (t + 1 < 8)
            sgk_stage(Bsrc + (size_t)(t + 1) * 16384, 256, Bb[(t + 1) & 1], tid);
        f32x4 acc[4][4];
        sgk_mfma(Bb[t & 1], af, acc, lg, lr);
        __syncthreads();

        const int fb = nsl * 512 + t * 64;
#pragma unroll
        for (int m = 0; m < 4; m++) {
#pragma unroll
            for (int rr = 0; rr < 4; rr++) {
                int q = wm + m * 16 + lg * 4 + rr;
                size_t qb = (size_t)(b * 256 + q) * 65536;
#pragma unroll
                for (int n = 0; n < 4; n++) {
                    int p = (fb + n * 16) >> 5;
                    int clo = ((fb + n * 16) & 31);
                    SAT[qb + (size_t)p * 256 + h * 32 + clo + lr] = f2bf(acc[m][n][rr]);
                }
            }
        }
    }
}

// ===========================================================================
// k_outT: out = W_out SAT^T + bias (stream).  grid 512: x = g (2 tokens each).
// Streams 8 N-tiles (2 tokens x 256 p).
// ===========================================================================
__global__ __launch_bounds__(256, 2) void k_outT(
    const unsigned short* __restrict__ SAT, const unsigned short* __restrict__ Wbf,
    const float* __restrict__ bias, float* __restrict__ out)
{
    const int g = blockIdx.x;

    __shared__ __align__(16) unsigned short Bb[2][16384];

    SGK_SETUP();

    s16x8 af[4][8];
    sgk_loadA(Wbf + 196608, af, wm, lg, lr);

    float bo[4][4];
#pragma unroll
    for (int m = 0; m < 4; m++)
#pragma unroll
        for (int rr = 0; rr < 4; rr++)
            bo[m][rr] = bias[wm + m * 16 + lg * 4 + rr];

    const unsigned short* Bsrc = SAT + (size_t)g * 131072 + srow * 256 + swoff;

    sgk_stage(Bsrc, 256, Bb[0], tid);
    __syncthreads();

    for (int t = 0; t < 8; t++) {
        if (t + 1 < 8)
            sgk_stage(Bsrc + (size_t)(t + 1) * 16384, 256, Bb[(t + 1) & 1], tid);
        f32x4 acc[4][4];
        sgk_mfma(Bb[t & 1], af, acc, lg, lr);
        __syncthreads();

        const int bs = g * 2 + (t >> 2);
        const int pb = (t & 3) * 64;
#pragma unroll
        for (int m = 0; m < 4; m++) {
#pragma unroll
            for (int rr = 0; rr < 4; rr++) {
                int o = wm + m * 16 + lg * 4 + rr;
                float* d = out + ((size_t)bs * 256 + o) * 256 + pb + lr;
#pragma unroll
                for (int n = 0; n < 4; n++)
                    d[n * 16] = acc[m][n][rr] + bo[m][rr];
            }
        }
    }
}

// ===========================================================================
// k_scores: Q K^T partials (classic dbuf, K=8192).  grid (16, 32).
// x = (mt*2+st)*4+kc, y = bh.  Sp[kc][bh][q][ks] f32 unscaled.
// ===========================================================================
DI void cls_stage(const unsigned short* gp, size_t stride,
                  unsigned short* lbase, int w) {
#pragma unroll
    for (int i = 0; i < 4; i++)
        GLOAD16(gp + (size_t)(i * 8) * stride, lbase + (w * 4 + i) * 512);
}

DI void cls_mfma(const unsigned short* __restrict__ Al,
                 const unsigned short* __restrict__ Bl,
                 f32x4 acc[4][4], int wm, int wn, int lg, int lr) {
#pragma unroll
    for (int kk = 0; kk < 2; kk++) {
        int off = (((kk * 4 + lg) ^ (lr & 7)) << 3);
        s16x8 af[4];
#pragma unroll
        for (int m = 0; m < 4; m++)
            af[m] = *(const s16x8*)&Al[(wm + m * 16 + lr) * 64 + off];
        s16x8 bf[4];
#pragma unroll
        for (int n = 0; n < 4; n++)
            bf[n] = *(const s16x8*)&Bl[(wn + n * 16 + lr) * 64 + off];
#pragma unroll
        for (int n = 0; n < 4; n++) {
            bf16x8 bv = asbf(bf[n]);
#pragma unroll
            for (int m = 0; m < 4; m++)
                acc[m][n] = MFMA16(asbf(af[m]), bv, acc[m][n]);
        }
    }
}

__global__ __launch_bounds__(256, 2) void k_scores(
    const unsigned short* __restrict__ Qb, const unsigned short* __restrict__ Kb,
    float* __restrict__ Sp)
{
    const int bh = blockIdx.y;
    const int kc = blockIdx.x & 3, st = (blockIdx.x >> 2) & 1, mt = blockIdx.x >> 3;
    const int tid = threadIdx.x, ln = tid & 63, w = tid >> 6;
    const int wm = (w >> 1) * 64, wn = (w & 1) * 64;
    const int lg = ln >> 4, lr = ln & 15;
    const int srow = ln >> 3;
    const int schk = (ln & 7) ^ srow;

    __shared__ __align__(16) unsigned short Ab[2][8192];
    __shared__ __align__(16) unsigned short Bb[2][8192];

    f32x4 acc[4][4];
    const f32x4 z4 = {0.f, 0.f, 0.f, 0.f};
#pragma unroll
    for (int m = 0; m < 4; m++)
#pragma unroll
        for (int n = 0; n < 4; n++) acc[m][n] = z4;

    const unsigned short* gA = Qb + (size_t)(bh * 256 + mt * 128 + w * 32 + srow) * 8192
                             + kc * 2048 + schk * 8;
    const unsigned short* gB = Kb + (size_t)(bh * 256 + st * 128 + w * 32 + srow) * 8192
                             + kc * 2048 + schk * 8;

    cls_stage(gA, 8192, Ab[0], w);
    cls_stage(gB, 8192, Bb[0], w);
    __syncthreads();
    for (int t = 0; t < 32; t++) {
        if (t + 1 < 32) {
            cls_stage(gA + (size_t)(t + 1) * 64, 8192, Ab[(t + 1) & 1], w);
            cls_stage(gB + (size_t)(t + 1) * 64, 8192, Bb[(t + 1) & 1], w);
        }
        cls_mfma(Ab[t & 1], Bb[t & 1], acc, wm, wn, lg, lr);
        __syncthreads();
    }

    float* dst = Sp + (size_t)kc * 2097152
               + (size_t)(bh * 256 + mt * 128 + wm) * 256 + st * 128 + wn;
#pragma unroll
    for (int m = 0; m < 4; m++) {
#pragma unroll
        for (int rr = 0; rr < 4; rr++) {
            float* d = dst + (size_t)(m * 16 + lg * 4 + rr) * 256 + lr;
#pragma unroll
            for (int n = 0; n < 4; n++)
                d[n * 16] = acc[m][n][rr];
        }
    }
}

// ===========================================================================
// k_softmax: sum 4 partials, scale, softmax -> P bf16.  grid 2048 x 256.
// ===========================================================================
__global__ __launch_bounds__(256) void k_softmax(
    const float* __restrict__ Sp, unsigned short* __restrict__ Pb)
{
    const int tid = threadIdx.x, ln = tid & 63;
    const int row = blockIdx.x * 4 + (tid >> 6);
    const float scale = 0.011048543456039806f;  // 1/sqrt(32*256)

    const float* p0 = Sp + (size_t)row * 256 + ln * 4;
    f32x4 v = *(const f32x4*)p0;
#pragma unroll
    for (int k = 1; k < 4; k++)
        v += *(const f32x4*)(p0 + (size_t)k * 2097152);
    v *= scale;

    float m = fmaxf(fmaxf(v.x, v.y), fmaxf(v.z, v.w));
#pragma unroll
    for (int off = 32; off; off >>= 1) m = fmaxf(m, __shfl_xor(m, off));
    float e0 = __expf(v.x - m), e1 = __expf(v.y - m);
    float e2 = __expf(v.z - m), e3 = __expf(v.w - m);
    float sum = e0 + e1 + e2 + e3;
#pragma unroll
    for (int off = 32; off; off >>= 1) sum += __shfl_xor(sum, off);
    float inv = 1.f / sum;
    s16x4 p = {(short)f2bf(e0 * inv), (short)f2bf(e1 * inv),
               (short)f2bf(e2 * inv), (short)f2bf(e3 * inv)};
    *(s16x4*)(Pb + (size_t)row * 256 + ln * 4) = p;
}

// ---------------------------------------------------------------------------
extern "C" void kernel_launch(void* const* d_in, const int* in_sizes, int n_in,
                              void* d_out, int out_size, void* d_ws, size_t ws_size,
                              hipStream_t stream)
{
    const float* seq  = (const float*)d_in[0];
    const float* Wqkv = (const float*)d_in[1];
    const float* Wout = (const float*)d_in[2];
    const float* bout = (const float*)d_in[3];

    // d_out: Q | K (dead before k_outT writes the final f32 output at base)
    unsigned short* Qb = (unsigned short*)d_out;
    unsigned short* Kb = Qb + 67108864;

    // d_ws: Vt | R (seqT -> Sp -> SAT) | Pb | Wbf
    unsigned short* Vt   = (unsigned short*)d_ws;
    unsigned short* seqT = Vt + 67108864;
    float*          Sp   = (float*)seqT;
    unsigned short* SAT  = seqT;
    unsigned short* Pb   = (unsigned short*)d_ws + 134217728;
    unsigned short* Wbf  = Pb + 2097152;

    float* out = (float*)d_out;

    k_prep<<<dim3(1024), dim3(64), 0, stream>>>(Wqkv, Wout, Wbf);
    k_tr<<<dim3(1024), dim3(256), 0, stream>>>(seq, seqT);
    k_qkT<<<dim3(512), dim3(256), 0, stream>>>(seqT, Wbf, Qb, Kb);
    k_vT<<<dim3(512), dim3(256), 0, stream>>>(seqT, Wbf, Vt);
    k_scores<<<dim3(16, 32), dim3(256), 0, stream>>>(Qb, Kb, Sp);
    k_softmax<<<dim3(2048), dim3(256), 0, stream>>>(Sp, Pb);
    k_avT<<<dim3(512), dim3(256), 0, stream>>>(Pb, Vt, SAT);
    k_outT<<<dim3(512), dim3(256), 0, stream>>>(SAT, Wbf, bout, out);
}